// Round 1
// baseline (84.283 us; speedup 1.0000x reference)
//
#include <hip/hip_runtime.h>

#define B_SZ   1024
#define OUT_SZ 512
#define IN_SZ  1024
#define KK     2048            // merged K: [x^2 | x] · [u^2 | -2u^2w]

#define MB 64                  // b rows per block
#define NB 64                  // o rows per block
#define KSPLIT 8
#define KSL (KK / KSPLIT)      // 256 k per block
#define CH  64                 // k per chunk
#define NCH (KSL / CH)         // 4 chunks per block
#define NKC (KK / CH)          // 32 chunks total
#define CHUNK_ENT 512          // 16B entries per chunk image per matrix: 2(s)*4(frag)*64(slot)

typedef __bf16 bf16x8 __attribute__((ext_vector_type(8)));
typedef float  f32x4  __attribute__((ext_vector_type(4)));

// workspace layout (bytes)
#define PART_BYTES ((size_t)KSPLIT * B_SZ * OUT_SZ * 4)               // 16 MB
#define AIMG_OFF   PART_BYTES
#define AIMG_BYTES ((size_t)(B_SZ / MB) * NKC * CHUNK_ENT * 16)       // 4 MB
#define BIMG_OFF   (AIMG_OFF + AIMG_BYTES)
#define BIMG_BYTES ((size_t)(OUT_SZ / NB) * NKC * CHUNK_ENT * 16)     // 2 MB
#define RB_OFF     (BIMG_OFF + BIMG_BYTES)

// ---------------------------------------------------------------------------
// Prep: build bf16 fragment images in the exact LDS layout rbf_gemm stages.
// Image entry e (one 16B slot = 8 k-contiguous bf16):
//   slot=e&63, frag=(e>>6)&3, s=(e>>8)&1, kc=(e>>9)&31, tile=e>>14
//   row = tile*64 + frag*16 + (slot&15);  k0 = kc*64 + s*32 + (slot>>4)*8
// A' rows are b (x-side): k<1024 -> x^2, else x.
// B' rows are o (u,w-side): k<1024 -> u^2, else -2*u^2*w.
// rbias[o] = sum_i (u*w)^2 in fp32 (the rank-1 term, removed from MFMA).
// ---------------------------------------------------------------------------
__global__ __launch_bounds__(256) void rbf_prep(
    const float* __restrict__ x, const float* __restrict__ w,
    const float* __restrict__ u, __bf16* __restrict__ Aimg,
    __bf16* __restrict__ Bimg, float* __restrict__ rbias)
{
    const int bid = blockIdx.x, t = threadIdx.x;
    if (bid < 1024) {                               // A image: 262144 entries
        const int e    = (bid << 8) + t;
        const int slot = e & 63;
        const int frag = (e >> 6) & 3;
        const int s    = (e >> 8) & 1;
        const int kc   = (e >> 9) & 31;
        const int mT   = e >> 14;
        const int row  = mT * 64 + frag * 16 + (slot & 15);
        const int k0   = kc * 64 + s * 32 + (slot >> 4) * 8;
        const float* src = &x[(size_t)row * IN_SZ + (k0 & (IN_SZ - 1))];
        float4 v0 = *(const float4*)src;
        float4 v1 = *(const float4*)(src + 4);
        float vv[8] = {v0.x, v0.y, v0.z, v0.w, v1.x, v1.y, v1.z, v1.w};
        bf16x8 o8;
        if (k0 < IN_SZ) {                           // wave-uniform branch (kc uniform)
            #pragma unroll
            for (int j = 0; j < 8; ++j) o8[j] = (__bf16)(vv[j] * vv[j]);
        } else {
            #pragma unroll
            for (int j = 0; j < 8; ++j) o8[j] = (__bf16)vv[j];
        }
        *(bf16x8*)&Aimg[(size_t)e * 8] = o8;
    } else if (bid < 1536) {                        // B image: 131072 entries
        const int e    = ((bid - 1024) << 8) + t;
        const int slot = e & 63;
        const int frag = (e >> 6) & 3;
        const int s    = (e >> 8) & 1;
        const int kc   = (e >> 9) & 31;
        const int nT   = e >> 14;
        const int row  = nT * 64 + frag * 16 + (slot & 15);
        const int k0   = kc * 64 + s * 32 + (slot >> 4) * 8;
        const size_t off = (size_t)row * IN_SZ + (k0 & (IN_SZ - 1));
        float4 u0 = *(const float4*)&u[off];
        float4 u1 = *(const float4*)&u[off + 4];
        float uu[8] = {u0.x, u0.y, u0.z, u0.w, u1.x, u1.y, u1.z, u1.w};
        bf16x8 o8;
        if (k0 < IN_SZ) {
            #pragma unroll
            for (int j = 0; j < 8; ++j) o8[j] = (__bf16)(uu[j] * uu[j]);
        } else {
            float4 w0 = *(const float4*)&w[off];
            float4 w1 = *(const float4*)&w[off + 4];
            float ww[8] = {w0.x, w0.y, w0.z, w0.w, w1.x, w1.y, w1.z, w1.w};
            #pragma unroll
            for (int j = 0; j < 8; ++j) o8[j] = (__bf16)(-2.f * uu[j] * uu[j] * ww[j]);
        }
        *(bf16x8*)&Bimg[(size_t)e * 8] = o8;
    } else {                                        // rbias: 16 blocks x 32 rows
        const int o = ((bid - 1536) << 5) + (t >> 3);
        const size_t base = (size_t)o * IN_SZ + (size_t)(t & 7) * 128;
        float s = 0.f;
        for (int k2 = 0; k2 < 128; k2 += 4) {
            float4 uu = *(const float4*)&u[base + k2];
            float4 ww = *(const float4*)&w[base + k2];
            float p0 = uu.x * ww.x, p1 = uu.y * ww.y;
            float p2 = uu.z * ww.z, p3 = uu.w * ww.w;
            s = fmaf(p0, p0, s); s = fmaf(p1, p1, s);
            s = fmaf(p2, p2, s); s = fmaf(p3, p3, s);
        }
        s += __shfl_xor(s, 1);                      // 8 lanes per row share t>>3
        s += __shfl_xor(s, 2);
        s += __shfl_xor(s, 4);
        if ((t & 7) == 0) rbias[o] = s;
    }
}

// direct global->LDS DMA, 16B per lane (dest = wave-uniform base + lane*16)
__device__ __forceinline__ void gld_lds16(const __bf16* g, __bf16* l) {
    __builtin_amdgcn_global_load_lds(
        (const __attribute__((address_space(1))) void*)g,
        (__attribute__((address_space(3))) void*)l, 16, 0, 0);
}

// ---------------------------------------------------------------------------
// GEMM: part[kz][b][o] = sum_{k in kz-slice} A'[b][k] * B'[o][k]
// Staging is pure global_load_lds (images are pre-arranged), LDS reads are
// lane-linear (zero bank conflicts), double-buffered, 1 barrier per chunk.
// ---------------------------------------------------------------------------
__global__ __launch_bounds__(256) void rbf_gemm(
    const __bf16* __restrict__ Aimg, const __bf16* __restrict__ Bimg,
    float* __restrict__ part)
{
    __shared__ __bf16 Asm[2][CHUNK_ENT * 8];        // 8 KB per buffer
    __shared__ __bf16 Bsm[2][CHUNK_ENT * 8];

    const int t = threadIdx.x, lane = t & 63;
    const int wv = t >> 6, wm = wv >> 1, wn = wv & 1;
    const int mT = blockIdx.x, nT = blockIdx.y, kz = blockIdx.z;

    f32x4 acc[2][2] = {};

    const __bf16* gA = &Aimg[(size_t)(mT * NKC + kz * NCH) * CHUNK_ENT * 8];
    const __bf16* gB = &Bimg[(size_t)(nT * NKC + kz * NCH) * CHUNK_ENT * 8];

    auto stage = [&](int buf, int c) {
        const __bf16* ga = gA + (size_t)c * CHUNK_ENT * 8;
        const __bf16* gb = gB + (size_t)c * CHUNK_ENT * 8;
        gld_lds16(ga + (size_t)t * 8,         &Asm[buf][t * 8]);
        gld_lds16(ga + (size_t)(t + 256) * 8, &Asm[buf][(t + 256) * 8]);
        gld_lds16(gb + (size_t)t * 8,         &Bsm[buf][t * 8]);
        gld_lds16(gb + (size_t)(t + 256) * 8, &Bsm[buf][(t + 256) * 8]);
    };

    stage(0, 0);
    #pragma unroll
    for (int c = 0; c < NCH; ++c) {
        __syncthreads();                            // drains vmcnt -> buf[c&1] ready
        if (c + 1 < NCH) stage((c + 1) & 1, c + 1); // prefetch behind MFMAs
        const __bf16* Ab = Asm[c & 1];
        const __bf16* Bb = Bsm[c & 1];
        #pragma unroll
        for (int s = 0; s < 2; ++s) {
            bf16x8 a0 = *(const bf16x8*)&Ab[((s * 4 + wm * 2    ) * 64 + lane) * 8];
            bf16x8 a1 = *(const bf16x8*)&Ab[((s * 4 + wm * 2 + 1) * 64 + lane) * 8];
            bf16x8 b0 = *(const bf16x8*)&Bb[((s * 4 + wn * 2    ) * 64 + lane) * 8];
            bf16x8 b1 = *(const bf16x8*)&Bb[((s * 4 + wn * 2 + 1) * 64 + lane) * 8];
            acc[0][0] = __builtin_amdgcn_mfma_f32_16x16x32_bf16(a0, b0, acc[0][0], 0, 0, 0);
            acc[0][1] = __builtin_amdgcn_mfma_f32_16x16x32_bf16(a0, b1, acc[0][1], 0, 0, 0);
            acc[1][0] = __builtin_amdgcn_mfma_f32_16x16x32_bf16(a1, b0, acc[1][0], 0, 0, 0);
            acc[1][1] = __builtin_amdgcn_mfma_f32_16x16x32_bf16(a1, b1, acc[1][1], 0, 0, 0);
        }
    }

    // C/D: col = lane&15 (o), row = quad*4 + reg (b) — proven mapping
    const int col = lane & 15, rq = lane >> 4;
    #pragma unroll
    for (int mi = 0; mi < 2; ++mi) {
        const int b = mT * MB + (wm * 2 + mi) * 16 + rq * 4;
        #pragma unroll
        for (int ni = 0; ni < 2; ++ni) {
            const int o = nT * NB + (wn * 2 + ni) * 16 + col;
            #pragma unroll
            for (int r = 0; r < 4; ++r)
                part[((size_t)kz * B_SZ + (b + r)) * OUT_SZ + o] = acc[mi][ni][r];
        }
    }
}

// ---------------------------------------------------------------------------
// Reduce: z = sum_kz part + r[o];  out = a + exp(-z)*(1-2a).  float4 per thread.
// ---------------------------------------------------------------------------
__global__ __launch_bounds__(256) void rbf_reduce(
    const float* __restrict__ part, const float* __restrict__ rbias,
    const float* __restrict__ andor, float* __restrict__ out)
{
    const int i4   = blockIdx.x * 256 + threadIdx.x;
    const int base = i4 * 4;
    f32x4 z = {};
    #pragma unroll
    for (int kz = 0; kz < KSPLIT; ++kz)
        z += *(const f32x4*)&part[(size_t)kz * (B_SZ * OUT_SZ) + base];
    const int o = base & (OUT_SZ - 1);
    f32x4 rb = *(const f32x4*)&rbias[o];
    f32x4 av = *(const f32x4*)&andor[o];
    f32x4 res;
    #pragma unroll
    for (int j = 0; j < 4; ++j) {
        float y = __expf(-(z[j] + rb[j]));
        res[j] = fmaf(y, 1.f - 2.f * av[j], av[j]);
    }
    *(f32x4*)&out[base] = res;
}

extern "C" void kernel_launch(void* const* d_in, const int* in_sizes, int n_in,
                              void* d_out, int out_size, void* d_ws, size_t ws_size,
                              hipStream_t stream) {
    const float* x = (const float*)d_in[0];   // [B, IN]
    const float* w = (const float*)d_in[1];   // [OUT, IN]
    const float* u = (const float*)d_in[2];   // [OUT, IN]
    const float* a = (const float*)d_in[3];   // [1, OUT]
    float* out = (float*)d_out;               // [B, OUT]

    float*  part  = (float*)d_ws;
    __bf16* Aimg  = (__bf16*)((char*)d_ws + AIMG_OFF);
    __bf16* Bimg  = (__bf16*)((char*)d_ws + BIMG_OFF);
    float*  rbias = (float*)((char*)d_ws + RB_OFF);

    rbf_prep  <<<dim3(1552),      dim3(256), 0, stream>>>(x, w, u, Aimg, Bimg, rbias);
    rbf_gemm  <<<dim3(16, 8, 8),  dim3(256), 0, stream>>>(Aimg, Bimg, part);
    rbf_reduce<<<dim3(512),       dim3(256), 0, stream>>>(part, rbias, a, out);
}